// Round 7
// baseline (272.237 us; speedup 1.0000x reference)
//
#include <hip/hip_runtime.h>
#include <math.h>

// Problem constants (fixed by setup_inputs)
#define W_ 192
#define H_ 192
#define D_ 160
#define B_ 2
#define XT 64             // x outputs per block (4 per thread)
#define YT 16             // y outputs per block
#define XP 34             // halo x-pairs (68 columns = 64+4)
#define HY 20             // raw halo rows (16+4)
#define CHUNK 10          // z outputs per block
#define PLANES (CHUNK + 4)
#define GXD 3
#define GYD 12
#define GZD 32            // 16 z-chunks x 2 batches
#define NBLK (GXD * GYD * GZD)   // 1152
#define CSP 35            // csum row stride in float2 (34 + 1 pad)
#define NTOT 11796480.0f  // 2*1*160*192*192

__device__ __forceinline__ float4 f4add(float4 a, float4 b) {
    return make_float4(a.x + b.x, a.y + b.y, a.z + b.z, a.w + b.w);
}
__device__ __forceinline__ float4 f4sub(float4 a, float4 b) {
    return make_float4(a.x - b.x, a.y - b.y, a.z - b.z, a.w - b.w);
}
// 5-tap x-window sums for 4 outputs from 8 consecutive column values
__device__ __forceinline__ float4 win8(float2 a, float2 b, float2 c, float2 d) {
    float W0 = a.x + a.y + b.x + b.y + c.x;
    float W1 = W0 + (c.y - a.x);
    float W2 = W1 + (d.x - a.y);
    float W3 = W2 + (d.y - b.x);
    return make_float4(W0, W1, W2, W3);
}

__global__ __launch_bounds__(256, 3) void lncc_main(const float* __restrict__ src,
                                                    const float* __restrict__ tgt,
                                                    float* __restrict__ partial) {
    // raw: interleaved {s,t} x-pairs, single-buffered (round-6 2-barrier scheme).
    // csum: y-window sums per x-halo column, pair-packed float2, 5 arrays.
    __shared__ float4 raw[HY][XP];                  // 10.9 KB
    __shared__ float2 csS[YT][CSP], csT[YT][CSP],   // 5 x 4.48 KB = 22.4 KB
                      csA[YT][CSP], csB[YT][CSP], csC[YT][CSP];
    __shared__ float wsum[4];

    const int tid = threadIdx.x;                     // 256x1 block
    const int xg  = tid & 15;                        // x-group (4 outputs each)
    const int ty  = tid >> 4;                        // y row 0..15
    const int bz  = blockIdx.z;
    const int b   = bz >> 4;                         // 16 z-chunks per batch
    const int z0  = (bz & 15) * CHUNK;
    const int bx0 = blockIdx.x * XT - 2;             // even -> float2-aligned
    const int by0 = blockIdx.y * YT - 2;

    // staging: 680 float2-pair slots; thread owns slots tid, tid+256, (+512 if tid<168)
    const int  sA_r = tid / 34,         sA_c = tid - sA_r * 34;
    const int  sB   = tid + 256;
    const int  sB_r = sB / 34,          sB_c = sB - sB_r * 34;
    const int  sC   = tid + 512;
    const int  sC_r = sC / 34,          sC_c = sC - sC_r * 34;
    const bool has3 = (tid < 168);

    auto load_slot = [&](int r, int c, int zp, float2& vS, float2& vT) {
        vS = make_float2(0.f, 0.f); vT = make_float2(0.f, 0.f);
        const int gx = bx0 + 2 * c, gy = by0 + r;
        if ((unsigned)zp < (unsigned)D_ && (unsigned)gy < (unsigned)H_ &&
            (unsigned)gx < (unsigned)W_) {
            const size_t off = (size_t)(b * D_ + zp) * (size_t)(H_ * W_)
                             + (size_t)gy * W_ + (size_t)gx;
            vS = *(const float2*)(src + off);
            vT = *(const float2*)(tgt + off);
        }
    };
    auto store_slot = [&](int r, int c, float2 vS, float2 vT) {
        raw[r][c] = make_float4(vS.x, vT.x, vS.y, vT.y);
    };

    // phase1 decode: 136 tasks = 34 x-pairs x 4 y-groups (4 output rows each)
    const bool p1act = (tid < 136);
    const int  p1p   = tid % 34;
    const int  p1g   = tid / 34;

    // z-ring: 5 planes x 5 quantities x float4 (4 x-outputs) = 100 VGPRs,
    // named registers rotated by assignment (round-2 lesson: arrays -> scratch)
    float4 q0S={0,0,0,0},q0T={0,0,0,0},q0A={0,0,0,0},q0B={0,0,0,0},q0C={0,0,0,0};
    float4 q1S={0,0,0,0},q1T={0,0,0,0},q1A={0,0,0,0},q1B={0,0,0,0},q1C={0,0,0,0};
    float4 q2S={0,0,0,0},q2T={0,0,0,0},q2A={0,0,0,0},q2B={0,0,0,0},q2C={0,0,0,0};
    float4 q3S={0,0,0,0},q3T={0,0,0,0},q3A={0,0,0,0},q3B={0,0,0,0},q3C={0,0,0,0};
    float4 q4S={0,0,0,0},q4T={0,0,0,0},q4A={0,0,0,0},q4B={0,0,0,0},q4C={0,0,0,0};
    float4 zS={0,0,0,0},zT={0,0,0,0},zA={0,0,0,0},zB={0,0,0,0},zC={0,0,0,0};
    float4 lsum = {0,0,0,0};

    // prologue: stage plane zp = z0-2
    {
        float2 aS, aT, bS, bT, cS, cT;
        load_slot(sA_r, sA_c, z0 - 2, aS, aT);
        load_slot(sB_r, sB_c, z0 - 2, bS, bT);
        if (has3) load_slot(sC_r, sC_c, z0 - 2, cS, cT);
        store_slot(sA_r, sA_c, aS, aT);
        store_slot(sB_r, sB_c, bS, bT);
        if (has3) store_slot(sC_r, sC_c, cS, cT);
    }

    for (int i = 0; i < PLANES; ++i) {
        __syncthreads();   // barrier A: raw(i) visible; phase2(i-1) csum reads done
        // -- prefetch plane i+1 into registers --
        float2 aS, aT, bS, bT, cS, cT;
        const bool haveNext = (i + 1 < PLANES);
        if (haveNext) {
            const int zpn = z0 - 1 + i;
            load_slot(sA_r, sA_c, zpn, aS, aT);
            load_slot(sB_r, sB_c, zpn, bS, bT);
            if (has3) load_slot(sC_r, sC_c, zpn, cS, cT);
        }
        // -- phase1: y-window sums from raw, y-slide over 4 output rows --
        if (p1act) {
            const int p = p1p, y0g = p1g * 4;
            float4 r0 = raw[y0g + 0][p];
            float4 r1 = raw[y0g + 1][p];
            float4 r2 = raw[y0g + 2][p];
            float4 r3 = raw[y0g + 3][p];
            float4 r4 = raw[y0g + 4][p];
            float S0 = r0.x + r1.x + r2.x + r3.x + r4.x;
            float S1 = r0.z + r1.z + r2.z + r3.z + r4.z;
            float T0 = r0.y + r1.y + r2.y + r3.y + r4.y;
            float T1 = r0.w + r1.w + r2.w + r3.w + r4.w;
            float A0 = fmaf(r4.x, r4.x, fmaf(r3.x, r3.x, fmaf(r2.x, r2.x, fmaf(r1.x, r1.x, r0.x * r0.x))));
            float A1 = fmaf(r4.z, r4.z, fmaf(r3.z, r3.z, fmaf(r2.z, r2.z, fmaf(r1.z, r1.z, r0.z * r0.z))));
            float B0 = fmaf(r4.y, r4.y, fmaf(r3.y, r3.y, fmaf(r2.y, r2.y, fmaf(r1.y, r1.y, r0.y * r0.y))));
            float B1 = fmaf(r4.w, r4.w, fmaf(r3.w, r3.w, fmaf(r2.w, r2.w, fmaf(r1.w, r1.w, r0.w * r0.w))));
            float C0 = fmaf(r4.x, r4.y, fmaf(r3.x, r3.y, fmaf(r2.x, r2.y, fmaf(r1.x, r1.y, r0.x * r0.y))));
            float C1 = fmaf(r4.z, r4.w, fmaf(r3.z, r3.w, fmaf(r2.z, r2.w, fmaf(r1.z, r1.w, r0.z * r0.w))));
            csS[y0g][p] = make_float2(S0, S1);
            csT[y0g][p] = make_float2(T0, T1);
            csA[y0g][p] = make_float2(A0, A1);
            csB[y0g][p] = make_float2(B0, B1);
            csC[y0g][p] = make_float2(C0, C1);
            #pragma unroll
            for (int m = 1; m <= 3; ++m) {
                float4 rn = raw[y0g + 4 + m][p];
                S0 += rn.x - r0.x;  S1 += rn.z - r0.z;
                T0 += rn.y - r0.y;  T1 += rn.w - r0.w;
                A0 = fmaf(rn.x, rn.x, fmaf(-r0.x, r0.x, A0));
                A1 = fmaf(rn.z, rn.z, fmaf(-r0.z, r0.z, A1));
                B0 = fmaf(rn.y, rn.y, fmaf(-r0.y, r0.y, B0));
                B1 = fmaf(rn.w, rn.w, fmaf(-r0.w, r0.w, B1));
                C0 = fmaf(rn.x, rn.y, fmaf(-r0.x, r0.y, C0));
                C1 = fmaf(rn.z, rn.w, fmaf(-r0.z, r0.w, C1));
                r0 = r1; r1 = r2; r2 = r3; r3 = r4; r4 = rn;
                csS[y0g + m][p] = make_float2(S0, S1);
                csT[y0g + m][p] = make_float2(T0, T1);
                csA[y0g + m][p] = make_float2(A0, A1);
                csB[y0g + m][p] = make_float2(B0, B1);
                csC[y0g + m][p] = make_float2(C0, C1);
            }
        }
        __syncthreads();   // barrier B: raw reads done; csum(i) visible
        // -- store prefetched plane i+1 (vmcnt wait overlaps phase2 below) --
        if (haveNext) {
            store_slot(sA_r, sA_c, aS, aT);
            store_slot(sB_r, sB_c, bS, bT);
            if (has3) store_slot(sC_r, sC_c, cS, cT);
        }
        // -- phase2: x-window (4 outputs/thread) + z sliding window + epilogue --
        {
            const int p2 = 2 * xg;
            float4 ysS, ysT, ysA, ysB, ysC;
            { float2 a = csS[ty][p2], b2 = csS[ty][p2+1], c2 = csS[ty][p2+2], d = csS[ty][p2+3];
              ysS = win8(a, b2, c2, d); }
            { float2 a = csT[ty][p2], b2 = csT[ty][p2+1], c2 = csT[ty][p2+2], d = csT[ty][p2+3];
              ysT = win8(a, b2, c2, d); }
            { float2 a = csA[ty][p2], b2 = csA[ty][p2+1], c2 = csA[ty][p2+2], d = csA[ty][p2+3];
              ysA = win8(a, b2, c2, d); }
            { float2 a = csB[ty][p2], b2 = csB[ty][p2+1], c2 = csB[ty][p2+2], d = csB[ty][p2+3];
              ysB = win8(a, b2, c2, d); }
            { float2 a = csC[ty][p2], b2 = csC[ty][p2+1], c2 = csC[ty][p2+2], d = csC[ty][p2+3];
              ysC = win8(a, b2, c2, d); }
            zS = f4add(zS, f4sub(ysS, q0S));
            zT = f4add(zT, f4sub(ysT, q0T));
            zA = f4add(zA, f4sub(ysA, q0A));
            zB = f4add(zB, f4sub(ysB, q0B));
            zC = f4add(zC, f4sub(ysC, q0C));
            q0S=q1S; q0T=q1T; q0A=q1A; q0B=q1B; q0C=q1C;
            q1S=q2S; q1T=q2T; q1A=q2A; q1B=q2B; q1C=q2C;
            q2S=q3S; q2T=q3T; q2A=q3A; q2B=q3B; q2C=q3C;
            q3S=q4S; q3T=q4T; q3A=q4A; q3B=q4B; q3C=q4C;
            q4S=ysS; q4T=ysT; q4A=ysA; q4B=ysB; q4C=ysC;
            if (i >= 4) {
                const float inv = 1.0f / 125.0f;
                auto accum = [&](float s, float t, float a2, float b2, float c2, float& acc) {
                    float ms = s * inv, mt = t * inv;
                    float vs = fmaf(-ms, ms, a2 * inv);
                    float vt = fmaf(-mt, mt, b2 * inv);
                    float cr = fmaf(-ms, mt, c2 * inv);
                    float den = fmaf(vs, vt, 1e-5f);
                    acc = fmaf(cr * cr, __builtin_amdgcn_rcpf(den), acc);
                };
                accum(zS.x, zT.x, zA.x, zB.x, zC.x, lsum.x);
                accum(zS.y, zT.y, zA.y, zB.y, zC.y, lsum.y);
                accum(zS.z, zT.z, zA.z, zB.z, zC.z, lsum.z);
                accum(zS.w, zT.w, zA.w, zB.w, zC.w, lsum.w);
            }
        }
    }

    // block reduction -> per-block partial
    float ls = (lsum.x + lsum.y) + (lsum.z + lsum.w);
    #pragma unroll
    for (int off = 32; off > 0; off >>= 1)
        ls += __shfl_down(ls, off, 64);
    if ((tid & 63) == 0) wsum[tid >> 6] = ls;
    __syncthreads();
    if (tid == 0) {
        const int bid = (blockIdx.z * GYD + blockIdx.y) * GXD + blockIdx.x;
        partial[bid] = wsum[0] + wsum[1] + wsum[2] + wsum[3];
    }
}

__global__ __launch_bounds__(256) void lncc_finalize(const float* __restrict__ partial,
                                                     float* __restrict__ out) {
    __shared__ float ws[4];
    const int t = threadIdx.x;
    float s = 0.0f;
    for (int i = t; i < NBLK; i += 256) s += partial[i];
    #pragma unroll
    for (int off = 32; off > 0; off >>= 1) s += __shfl_down(s, off, 64);
    if ((t & 63) == 0) ws[t >> 6] = s;
    __syncthreads();
    if (t == 0) {
        float tot = ws[0] + ws[1] + ws[2] + ws[3];
        float loss = 1.0f - tot * (1.0f / NTOT);
        if (isnan(loss) || isinf(loss)) loss = 1.0f;
        *out = loss;
    }
}

extern "C" void kernel_launch(void* const* d_in, const int* in_sizes, int n_in,
                              void* d_out, int out_size, void* d_ws, size_t ws_size,
                              hipStream_t stream) {
    const float* src = (const float*)d_in[0];
    const float* tgt = (const float*)d_in[1];
    float* out = (float*)d_out;
    float* partial = (float*)d_ws;   // NBLK floats of scratch

    dim3 grid(GXD, GYD, GZD);        // 3 x 12 x 32 = 1152 blocks
    dim3 block(256, 1, 1);
    lncc_main<<<grid, block, 0, stream>>>(src, tgt, partial);
    lncc_finalize<<<dim3(1), dim3(256), 0, stream>>>(partial, out);
}

// Round 8
// 201.704 us; speedup vs baseline: 1.3497x; 1.3497x over previous
//
#include <hip/hip_runtime.h>
#include <math.h>

// Problem constants (fixed by setup_inputs)
#define W_ 192
#define H_ 192
#define D_ 160
#define B_ 2
#define XT 32             // x outputs per block (2 per thread)
#define YT 16             // y outputs per block
#define HY 20             // raw halo rows (16+4)
#define NPAIR 18          // halo x-pairs (36 columns = 32+4)
#define CHUNK 20          // z outputs per block
#define PLANES (CHUNK + 4)
#define GXD 6
#define GYD 12
#define GZD 16            // 8 z-chunks x 2 batches
#define NBLK (GXD * GYD * GZD)   // 1152
#define NTOT 11796480.0f  // 2*1*160*192*192

__device__ __forceinline__ float2 f2add(float2 u, float2 v) { return make_float2(u.x + v.x, u.y + v.y); }
__device__ __forceinline__ float2 f2sub(float2 u, float2 v) { return make_float2(u.x - v.x, u.y - v.y); }

__global__ __launch_bounds__(256) void lncc_main(const float* __restrict__ src,
                                                 const float* __restrict__ tgt,
                                                 float* __restrict__ partial) {
    // raw: interleaved {s,t} x-pairs {s(2p),t(2p),s(2p+1),t(2p+1)}, single-buffered.
    // cs: y-window column sums. {S,T,A,B} packed as float4 per column; column
    // slot = parity*18 + pair (parity split keeps writes/reads bank-uniform).
    // {C} stored per pair as float2. LDS total ~18 KB.
    __shared__ float4 raw[HY][NPAIR + 1];        // 6.1 KB
    __shared__ float4 csQ[YT][2 * NPAIR + 1];    // 9.5 KB  (slots 0..17 even, 18..35 odd)
    __shared__ float2 csC[YT][NPAIR + 1];        // 2.4 KB
    __shared__ float wsum[4];

    const int tid = threadIdx.x;                 // 256x1
    const int tx  = tid & 15;
    const int ty  = tid >> 4;
    const int bz  = blockIdx.z;
    const int b   = bz >> 3;                     // 8 z-chunks per batch
    const int z0  = (bz & 7) * CHUNK;
    const int bx0 = blockIdx.x * XT - 2;         // even -> float2-aligned
    const int by0 = blockIdx.y * YT - 2;

    // staging: 360 float2-pair slots (20 rows x 18 pairs)
    const int  sA_r = tid / 18,  sA_c = tid - sA_r * 18;
    const int  sB   = tid + 256;
    const int  sB_r = sB / 18,   sB_c = sB - sB_r * 18;
    const bool has2 = (tid < 104);

    auto load_slot = [&](int r, int c, int zp, float2& vS, float2& vT) {
        vS = make_float2(0.f, 0.f); vT = make_float2(0.f, 0.f);
        const int gx = bx0 + 2 * c, gy = by0 + r;
        if ((unsigned)zp < (unsigned)D_ && (unsigned)gy < (unsigned)H_ &&
            (unsigned)gx < (unsigned)W_) {
            const size_t off = (size_t)(b * D_ + zp) * (size_t)(H_ * W_)
                             + (size_t)gy * W_ + (size_t)gx;
            vS = *(const float2*)(src + off);
            vT = *(const float2*)(tgt + off);
        }
    };
    auto store_slot = [&](int r, int c, float2 vS, float2 vT) {
        raw[r][c] = make_float4(vS.x, vT.x, vS.y, vT.y);
    };

    // phase1 decode: 72 tasks = 18 pairs x 4 y-groups (4 output rows each)
    const bool p1act = (tid < 72);
    const int  p1p   = tid % 18;
    const int  p1g   = tid / 18;

    // z-ring: 5 planes x 5 quantities x float2 = 50 VGPR, NAMED registers
    // rotated by assignment (round-2/7 lesson: indexed arrays -> scratch spill)
    float2 q0S={0,0},q0T={0,0},q0A={0,0},q0B={0,0},q0C={0,0};
    float2 q1S={0,0},q1T={0,0},q1A={0,0},q1B={0,0},q1C={0,0};
    float2 q2S={0,0},q2T={0,0},q2A={0,0},q2B={0,0},q2C={0,0};
    float2 q3S={0,0},q3T={0,0},q3A={0,0},q3B={0,0},q3C={0,0};
    float2 q4S={0,0},q4T={0,0},q4A={0,0},q4B={0,0},q4C={0,0};
    float2 zS={0,0},zT={0,0},zA={0,0},zB={0,0},zC={0,0};
    float2 lsum = make_float2(0.f, 0.f);

    // prologue: stage plane zp = z0-2
    {
        float2 aS, aT, bS, bT;
        load_slot(sA_r, sA_c, z0 - 2, aS, aT);
        if (has2) load_slot(sB_r, sB_c, z0 - 2, bS, bT);
        store_slot(sA_r, sA_c, aS, aT);
        if (has2) store_slot(sB_r, sB_c, bS, bT);
    }

    for (int i = 0; i < PLANES; ++i) {
        __syncthreads();   // barrier A: raw(i) visible; phase2(i-1) cs reads done
        // -- prefetch plane i+1 into registers --
        float2 aS, aT, bS, bT;
        const bool haveNext = (i + 1 < PLANES);
        if (haveNext) {
            const int zpn = z0 - 1 + i;
            load_slot(sA_r, sA_c, zpn, aS, aT);
            if (has2) load_slot(sB_r, sB_c, zpn, bS, bT);
        }
        // -- phase1: y-window column sums via y-slide over 4 output rows --
        if (p1act) {
            const int p = p1p, y0g = p1g * 4;
            float4 r0 = raw[y0g + 0][p];
            float4 r1 = raw[y0g + 1][p];
            float4 r2 = raw[y0g + 2][p];
            float4 r3 = raw[y0g + 3][p];
            float4 r4 = raw[y0g + 4][p];
            float S0 = r0.x + r1.x + r2.x + r3.x + r4.x;
            float T0 = r0.y + r1.y + r2.y + r3.y + r4.y;
            float S1 = r0.z + r1.z + r2.z + r3.z + r4.z;
            float T1 = r0.w + r1.w + r2.w + r3.w + r4.w;
            float A0 = fmaf(r4.x, r4.x, fmaf(r3.x, r3.x, fmaf(r2.x, r2.x, fmaf(r1.x, r1.x, r0.x * r0.x))));
            float B0 = fmaf(r4.y, r4.y, fmaf(r3.y, r3.y, fmaf(r2.y, r2.y, fmaf(r1.y, r1.y, r0.y * r0.y))));
            float A1 = fmaf(r4.z, r4.z, fmaf(r3.z, r3.z, fmaf(r2.z, r2.z, fmaf(r1.z, r1.z, r0.z * r0.z))));
            float B1 = fmaf(r4.w, r4.w, fmaf(r3.w, r3.w, fmaf(r2.w, r2.w, fmaf(r1.w, r1.w, r0.w * r0.w))));
            float C0 = fmaf(r4.x, r4.y, fmaf(r3.x, r3.y, fmaf(r2.x, r2.y, fmaf(r1.x, r1.y, r0.x * r0.y))));
            float C1 = fmaf(r4.z, r4.w, fmaf(r3.z, r3.w, fmaf(r2.z, r2.w, fmaf(r1.z, r1.w, r0.z * r0.w))));
            csQ[y0g][p]          = make_float4(S0, T0, A0, B0);
            csQ[y0g][18 + p]     = make_float4(S1, T1, A1, B1);
            csC[y0g][p]          = make_float2(C0, C1);
            #pragma unroll
            for (int m = 1; m <= 3; ++m) {
                float4 rn = raw[y0g + 4 + m][p];
                S0 += rn.x - r0.x;  T0 += rn.y - r0.y;
                S1 += rn.z - r0.z;  T1 += rn.w - r0.w;
                A0 = fmaf(rn.x, rn.x, fmaf(-r0.x, r0.x, A0));
                B0 = fmaf(rn.y, rn.y, fmaf(-r0.y, r0.y, B0));
                A1 = fmaf(rn.z, rn.z, fmaf(-r0.z, r0.z, A1));
                B1 = fmaf(rn.w, rn.w, fmaf(-r0.w, r0.w, B1));
                C0 = fmaf(rn.x, rn.y, fmaf(-r0.x, r0.y, C0));
                C1 = fmaf(rn.z, rn.w, fmaf(-r0.z, r0.w, C1));
                r0 = r1; r1 = r2; r2 = r3; r3 = r4; r4 = rn;
                csQ[y0g + m][p]      = make_float4(S0, T0, A0, B0);
                csQ[y0g + m][18 + p] = make_float4(S1, T1, A1, B1);
                csC[y0g + m][p]      = make_float2(C0, C1);
            }
        }
        __syncthreads();   // barrier B: raw reads done; cs(i) visible
        // -- store prefetched plane i+1 (vmcnt wait overlaps phase2 below) --
        if (haveNext) {
            store_slot(sA_r, sA_c, aS, aT);
            if (has2) store_slot(sB_r, sB_c, bS, bT);
        }
        // -- phase2: x-window (2 outputs/thread) + z sliding window + epilogue --
        {
            // columns for outputs 2tx, 2tx+1: halo cols 2tx..2tx+5
            float4 E0 = csQ[ty][tx];          // col 2tx
            float4 E1 = csQ[ty][tx + 1];      // col 2tx+2
            float4 E2 = csQ[ty][tx + 2];      // col 2tx+4
            float4 O0 = csQ[ty][18 + tx];     // col 2tx+1
            float4 O1 = csQ[ty][18 + tx + 1]; // col 2tx+3
            float4 O2 = csQ[ty][18 + tx + 2]; // col 2tx+5
            float2 cc0 = csC[ty][tx];         // C at cols 2tx, 2tx+1
            float2 cc1 = csC[ty][tx + 1];     // cols 2tx+2, 2tx+3
            float2 cc2 = csC[ty][tx + 2];     // cols 2tx+4, 2tx+5
            float2 ysS, ysT, ysA, ysB, ysC;
            { float w0 = E0.x + O0.x + E1.x + O1.x + E2.x; ysS = make_float2(w0, w0 - E0.x + O2.x); }
            { float w0 = E0.y + O0.y + E1.y + O1.y + E2.y; ysT = make_float2(w0, w0 - E0.y + O2.y); }
            { float w0 = E0.z + O0.z + E1.z + O1.z + E2.z; ysA = make_float2(w0, w0 - E0.z + O2.z); }
            { float w0 = E0.w + O0.w + E1.w + O1.w + E2.w; ysB = make_float2(w0, w0 - E0.w + O2.w); }
            { float w0 = cc0.x + cc0.y + cc1.x + cc1.y + cc2.x; ysC = make_float2(w0, w0 - cc0.x + cc2.y); }
            zS = f2add(zS, f2sub(ysS, q0S));
            zT = f2add(zT, f2sub(ysT, q0T));
            zA = f2add(zA, f2sub(ysA, q0A));
            zB = f2add(zB, f2sub(ysB, q0B));
            zC = f2add(zC, f2sub(ysC, q0C));
            q0S=q1S; q0T=q1T; q0A=q1A; q0B=q1B; q0C=q1C;
            q1S=q2S; q1T=q2T; q1A=q2A; q1B=q2B; q1C=q2C;
            q2S=q3S; q2T=q3T; q2A=q3A; q2B=q3B; q2C=q3C;
            q3S=q4S; q3T=q4T; q3A=q4A; q3B=q4B; q3C=q4C;
            q4S=ysS; q4T=ysT; q4A=ysA; q4B=ysB; q4C=ysC;
            if (i >= 4) {
                const float inv = 1.0f / 125.0f;
                {   // output x = 2tx
                    float ms = zS.x * inv, mt = zT.x * inv;
                    float vs = fmaf(-ms, ms, zA.x * inv);
                    float vt = fmaf(-mt, mt, zB.x * inv);
                    float cr = fmaf(-ms, mt, zC.x * inv);
                    float den = fmaf(vs, vt, 1e-5f);
                    lsum.x = fmaf(cr * cr, __builtin_amdgcn_rcpf(den), lsum.x);
                }
                {   // output x = 2tx+1
                    float ms = zS.y * inv, mt = zT.y * inv;
                    float vs = fmaf(-ms, ms, zA.y * inv);
                    float vt = fmaf(-mt, mt, zB.y * inv);
                    float cr = fmaf(-ms, mt, zC.y * inv);
                    float den = fmaf(vs, vt, 1e-5f);
                    lsum.y = fmaf(cr * cr, __builtin_amdgcn_rcpf(den), lsum.y);
                }
            }
        }
    }

    // block reduction -> per-block partial
    float ls = lsum.x + lsum.y;
    #pragma unroll
    for (int off = 32; off > 0; off >>= 1)
        ls += __shfl_down(ls, off, 64);
    if ((tid & 63) == 0) wsum[tid >> 6] = ls;
    __syncthreads();
    if (tid == 0) {
        const int bid = (blockIdx.z * GYD + blockIdx.y) * GXD + blockIdx.x;
        partial[bid] = wsum[0] + wsum[1] + wsum[2] + wsum[3];
    }
}

__global__ __launch_bounds__(256) void lncc_finalize(const float* __restrict__ partial,
                                                     float* __restrict__ out) {
    __shared__ float ws[4];
    const int t = threadIdx.x;
    float s = 0.0f;
    for (int i = t; i < NBLK; i += 256) s += partial[i];
    #pragma unroll
    for (int off = 32; off > 0; off >>= 1) s += __shfl_down(s, off, 64);
    if ((t & 63) == 0) ws[t >> 6] = s;
    __syncthreads();
    if (t == 0) {
        float tot = ws[0] + ws[1] + ws[2] + ws[3];
        float loss = 1.0f - tot * (1.0f / NTOT);
        if (isnan(loss) || isinf(loss)) loss = 1.0f;
        *out = loss;
    }
}

extern "C" void kernel_launch(void* const* d_in, const int* in_sizes, int n_in,
                              void* d_out, int out_size, void* d_ws, size_t ws_size,
                              hipStream_t stream) {
    const float* src = (const float*)d_in[0];
    const float* tgt = (const float*)d_in[1];
    float* out = (float*)d_out;
    float* partial = (float*)d_ws;   // NBLK floats of scratch

    dim3 grid(GXD, GYD, GZD);        // 6 x 12 x 16 = 1152 blocks
    dim3 block(256, 1, 1);
    lncc_main<<<grid, block, 0, stream>>>(src, tgt, partial);
    lncc_finalize<<<dim3(1), dim3(256), 0, stream>>>(partial, out);
}